// Round 17
// baseline (709.501 us; speedup 1.0000x reference)
//
#include <hip/hip_runtime.h>
#include <hip/hip_fp16.h>
#include <cstdint>

// 2-layer GAT, PyG GATConv semantics (concat heads, self-loops, segment softmax).
// R17: HYPOTHESIS TEST — the ~55-67us/GEMM floor survived 7 in-kernel
// structures (VALU/MFMA, LDS/none, barriers/none, 512/1563 blocks, batched/
// serial loads), while R15 ablation showed loads-only + stores-only + shell
// are all cheap. Last un-varied dimension: the dispatch boundary. This round
// fuses gemm1 -> agg1 -> gemm2 -> agg2 into ONE persistent kernel (256 blocks,
// guaranteed co-resident) with manual grid barriers (device-scope atomics +
// threadfence; counters ifill'd to 0 each call => graph-replay-safe).
// If total collapses to ~150us, the floor was per-dispatch overhead; if flat,
// the floor is in-wave and R18 goes to disasm.
// Components otherwise: fused att-dot GEMM columns (R14), fp16 h table (R8),
// channel-paired agg (R9), CSR bucketed build (R7).
// Softmax max-subtraction omitted: shift-invariant, |e| <= ~10 so exp() safe in f32.

#define CH 4096
#define MAXB 512
#define SCAP 6144
#define GRID_FUSED 256  // 1 block/CU guaranteed resident (capacity 2/CU via launch_bounds)

using f16x8 = __attribute__((ext_vector_type(8))) _Float16;
using f32x4 = __attribute__((ext_vector_type(4))) float;

__device__ __forceinline__ float lrelu(float v) { return fmaxf(v, 0.2f * v); }

__global__ void ifill_kernel(int* __restrict__ p, int v, int n) {
  int i = blockIdx.x * blockDim.x + threadIdx.x;
  if (i < n) p[i] = v;
}

// Augmented W'^T [80][K] fp16: c<64: W[k][c]; c=64+hd: W_hd@att_src_hd;
// c=68+hd: W_hd@att_dst_hd; c>=72: 0.
__global__ void wprep2_kernel(const float* __restrict__ W,
                              const float* __restrict__ as,
                              const float* __restrict__ ad,
                              ushort* __restrict__ WT, int K) {
  int i = blockIdx.x * 256 + threadIdx.x;
  if (i >= 80 * K) return;
  int c = i / K, k = i % K;
  float v = 0.f;
  if (c < 64) {
    v = W[k * 64 + c];
  } else if (c < 68) {
    int hd = c - 64;
    for (int j = 0; j < 16; ++j) v += W[k * 64 + hd * 16 + j] * as[hd * 16 + j];
  } else if (c < 72) {
    int hd = c - 68;
    for (int j = 0; j < 16; ++j) v += W[k * 64 + hd * 16 + j] * ad[hd * 16 + j];
  }
  WT[c * K + k] = __half_as_ushort(__float2half_rn(v));
}

__global__ __launch_bounds__(256) void bucket_hist(const int* __restrict__ edst,
                                                   int E, int nbuck,
                                                   int* __restrict__ bucket_cnt) {
  __shared__ int hist[MAXB];
  const int t = threadIdx.x;
  for (int j = t; j < MAXB; j += 256) hist[j] = 0;
  __syncthreads();
  const int base = blockIdx.x * CH;
#pragma unroll
  for (int k = 0; k < CH / 256; ++k) {
    int e = base + k * 256 + t;
    if (e < E) atomicAdd(&hist[edst[e] >> 8], 1);
  }
  __syncthreads();
  for (int j = t; j < nbuck; j += 256) {
    int c = hist[j];
    if (c) atomicAdd(&bucket_cnt[j], c);
  }
}

__global__ __launch_bounds__(512) void bucket_scan(const int* __restrict__ bucket_cnt,
                                                   int* __restrict__ bucket_base,
                                                   int* __restrict__ bucket_cursor,
                                                   int nbuck) {
  __shared__ int part[512];
  const int t = threadIdx.x;
  int v = (t < nbuck) ? bucket_cnt[t] : 0;
  part[t] = v;
  __syncthreads();
  for (int off = 1; off < 512; off <<= 1) {
    int u = (t >= off) ? part[t - off] : 0;
    __syncthreads();
    part[t] += u;
    __syncthreads();
  }
  int ex = part[t] - v;
  if (t <= nbuck) {
    int w = (t < nbuck) ? ex : part[nbuck - 1];
    bucket_base[t] = w;
    if (t < nbuck) bucket_cursor[t] = w;
  }
}

__global__ __launch_bounds__(256) void place_kernel(const int* __restrict__ esrc,
                                                    const int* __restrict__ edst,
                                                    int E, int nbuck,
                                                    int* __restrict__ bucket_cursor,
                                                    unsigned int* __restrict__ pairs) {
  __shared__ int hist[MAXB];
  __shared__ int gbase[MAXB];
  __shared__ int rcnt[MAXB];
  const int t = threadIdx.x;
  for (int j = t; j < MAXB; j += 256) { hist[j] = 0; rcnt[j] = 0; }
  __syncthreads();
  const int base = blockIdx.x * CH;
  int b_[CH / 256];
  unsigned int p_[CH / 256];
#pragma unroll
  for (int k = 0; k < CH / 256; ++k) {
    int e = base + k * 256 + t;
    if (e < E) {
      int d = edst[e];
      int s = esrc[e];
      b_[k] = d >> 8;
      p_[k] = ((unsigned int)s << 8) | (unsigned int)(d & 255);
      atomicAdd(&hist[b_[k]], 1);
    } else {
      b_[k] = -1;
    }
  }
  __syncthreads();
  for (int j = t; j < nbuck; j += 256) {
    int c = hist[j];
    gbase[j] = c ? atomicAdd(&bucket_cursor[j], c) : 0;
  }
  __syncthreads();
#pragma unroll
  for (int k = 0; k < CH / 256; ++k) {
    if (b_[k] >= 0) {
      int r = atomicAdd(&rcnt[b_[k]], 1);
      pairs[gbase[b_[k]] + r] = p_[k];
    }
  }
}

__global__ __launch_bounds__(256) void bucket_build(
    const unsigned int* __restrict__ pairs, const int* __restrict__ bucket_base,
    int* __restrict__ ccol, int* __restrict__ start, int* __restrict__ endp,
    int n) {
  __shared__ int cnt[256];
  __shared__ int ls[256];
  __shared__ int csave[256];
  __shared__ int part[256];
  __shared__ int sorted[SCAP];
  const int t = threadIdx.x;
  const int b = blockIdx.x;
  const int d0 = b << 8;
  const int DR = min(256, n - d0);
  const int in_base = bucket_base[b];
  const int nloc = bucket_base[b + 1] - in_base;
  const int out_base = in_base + d0;

  cnt[t] = (t < DR) ? 1 : 0;
  __syncthreads();
  for (int i = t; i < nloc; i += 256)
    atomicAdd(&cnt[pairs[in_base + i] & 255u], 1);
  __syncthreads();
  int c = cnt[t];
  csave[t] = c;
  part[t] = c;
  __syncthreads();
#pragma unroll
  for (int off = 1; off < 256; off <<= 1) {
    int u = (t >= off) ? part[t - off] : 0;
    __syncthreads();
    part[t] += u;
    __syncthreads();
  }
  ls[t] = part[t] - c;
  __syncthreads();
  if (t < DR) {
    int s = out_base + ls[t];
    start[d0 + t] = s;
    endp[d0 + t] = s + csave[t];
    sorted[ls[t]] = d0 + t;
    cnt[t] = 1;
  }
  __syncthreads();
  for (int i = t; i < nloc; i += 256) {
    unsigned int p = pairs[in_base + i];
    int j = (int)(p & 255u);
    int r = atomicAdd(&cnt[j], 1);
    int pos = ls[j] + r;
    if (pos < SCAP) sorted[pos] = (int)(p >> 8);
  }
  __syncthreads();
  int tot = nloc + DR;
  if (tot > SCAP) tot = SCAP;
  for (int i = t; i < tot; i += 256) ccol[out_base + i] = sorted[i];
}

// Grid-wide barrier: device-scope atomics + release/acquire fences.
// All GRID_FUSED blocks are co-resident (1/CU guaranteed, capacity 2/CU).
__device__ __forceinline__ void gsync(int* bar, int idx, int goal) {
  __threadfence();   // release: my writes reach the coherent point
  __syncthreads();   // all warps of this block have fenced
  if (threadIdx.x == 0) {
    atomicAdd(&bar[idx], 1);
    while (atomicAdd(&bar[idx], 0) < goal) __builtin_amdgcn_s_sleep(2);
  }
  __syncthreads();
  __threadfence();   // acquire: discard stale cached lines
}

// GEMM phase (R14 body): 64-row tiles, grid-stride; fused att-dot columns;
// LDS-bounced full-line stores. Fragments: A row=lane&15, k=(lane>>4)*8+j;
// B col=lane&15 same k; D col=lane&15, row=(lane>>4)*4+reg.
template <int K, bool XHALF>
__device__ __forceinline__ void gemm_phase(
    const void* __restrict__ xin, const ushort* __restrict__ wt,
    __half* __restrict__ h, float* __restrict__ as_, float* __restrict__ ad_,
    int n, int ntiles, _Float16* hs, float* att) {
  const int tid = threadIdx.x;
  const int w = tid >> 6;
  const int lane = tid & 63;
  const int lr = lane & 15;
  const int kg = lane >> 4;
  constexpr int NS = K / 32;
  const ushort* wbase = wt + lr * K + kg * 8;

  for (int tile = blockIdx.x; tile < ntiles; tile += gridDim.x) {
    const int row0 = tile * 64;
    int rr = row0 + w * 16 + lr;
    if (rr > n - 1) rr = n - 1;

    f16x8 af[NS];
    if constexpr (!XHALF) {
      float4 av[NS][2];
      const float* xp = (const float*)xin + (long long)rr * K + kg * 8;
#pragma unroll
      for (int s = 0; s < NS; ++s) {
        av[s][0] = *(const float4*)(xp + s * 32);
        av[s][1] = *(const float4*)(xp + s * 32 + 4);
      }
#pragma unroll
      for (int s = 0; s < NS; ++s) {
        af[s][0] = (_Float16)av[s][0].x; af[s][1] = (_Float16)av[s][0].y;
        af[s][2] = (_Float16)av[s][0].z; af[s][3] = (_Float16)av[s][0].w;
        af[s][4] = (_Float16)av[s][1].x; af[s][5] = (_Float16)av[s][1].y;
        af[s][6] = (_Float16)av[s][1].z; af[s][7] = (_Float16)av[s][1].w;
      }
    } else {
      const ushort* xp = (const ushort*)xin + (long long)rr * K + kg * 8;
#pragma unroll
      for (int s = 0; s < NS; ++s)
        af[s] = *(const f16x8*)(xp + s * 32);
    }

    f32x4 acc[5] = {};
#pragma unroll
    for (int s = 0; s < NS; ++s)
#pragma unroll
      for (int ct = 0; ct < 5; ++ct) {
        f16x8 b = *(const f16x8*)(wbase + ct * 16 * K + s * 32);
        acc[ct] = __builtin_amdgcn_mfma_f32_16x16x32_f16(af[s], b, acc[ct], 0, 0, 0);
      }

    const int orow = w * 16 + kg * 4;
#pragma unroll
    for (int ct = 0; ct < 4; ++ct)
#pragma unroll
      for (int r = 0; r < 4; ++r)
        hs[(orow + r) * 88 + ct * 16 + lr] = (_Float16)acc[ct][r];
    if (lr < 8) {
#pragma unroll
      for (int r = 0; r < 4; ++r)
        att[(orow + r) * 12 + lr] = acc[4][r];
    }
    __syncthreads();
#pragma unroll
    for (int j = 0; j < 2; ++j) {
      int s = tid + j * 256;
      int row = s >> 3, seg = s & 7;
      if (row0 + row < n)
        *(uint4*)(h + (long long)(row0 + row) * 64 + seg * 8) =
            *(const uint4*)&hs[row * 88 + seg * 8];
    }
    if (tid < 64) {
      if (row0 + tid < n)
        *(float4*)(as_ + (long long)(row0 + tid) * 4) = *(const float4*)&att[tid * 12];
    } else if (tid < 128) {
      int t2 = tid - 64;
      if (row0 + t2 < n)
        *(float4*)(ad_ + (long long)(row0 + t2) * 4) = *(const float4*)&att[t2 * 12 + 4];
    }
    __syncthreads();
  }
}

// Aggregation phase (R9 body): half-wave per node, 2 nodes/wave, grid-stride.
__device__ __forceinline__ void agg_phase(
    const int* __restrict__ ccol, const int* __restrict__ start,
    const int* __restrict__ endp,
    const float* __restrict__ as_, const float* __restrict__ ad_,
    const __half2* __restrict__ h2, const float* __restrict__ bias,
    float* __restrict__ fout, __half2* __restrict__ hout, int n, int mode) {
  const int ngroups = (n + 7) / 8;
  const int hl = threadIdx.x & 31;
  const int hh = hl >> 3;
  for (int g = blockIdx.x; g < ngroups; g += gridDim.x) {
    const int node = g * 8 + (threadIdx.x >> 5);
    if (node >= n) continue;
    const float adv = ad_[node * 4 + hh];
    const int s0i = start[node];
    const int d = endp[node] - s0i;
    const int* cp = ccol + s0i;
    float ax = 0.f, ay = 0.f, den = 0.f;
    int i = 0;
    for (; i + 4 <= d; i += 4) {
      int s0 = cp[i], s1 = cp[i + 1], s2 = cp[i + 2], s3 = cp[i + 3];
      float p0 = __expf(lrelu(as_[s0 * 4 + hh] + adv));
      float p1 = __expf(lrelu(as_[s1 * 4 + hh] + adv));
      float p2 = __expf(lrelu(as_[s2 * 4 + hh] + adv));
      float p3 = __expf(lrelu(as_[s3 * 4 + hh] + adv));
      float2 h0 = __half22float2(h2[s0 * 32 + hl]);
      float2 h1 = __half22float2(h2[s1 * 32 + hl]);
      float2 h2v = __half22float2(h2[s2 * 32 + hl]);
      float2 h3 = __half22float2(h2[s3 * 32 + hl]);
      den += (p0 + p1) + (p2 + p3);
      ax = fmaf(p0, h0.x, ax); ay = fmaf(p0, h0.y, ay);
      ax = fmaf(p1, h1.x, ax); ay = fmaf(p1, h1.y, ay);
      ax = fmaf(p2, h2v.x, ax); ay = fmaf(p2, h2v.y, ay);
      ax = fmaf(p3, h3.x, ax); ay = fmaf(p3, h3.y, ay);
    }
    for (; i < d; ++i) {
      int s0 = cp[i];
      float p0 = __expf(lrelu(as_[s0 * 4 + hh] + adv));
      float2 h0 = __half22float2(h2[s0 * 32 + hl]);
      den += p0;
      ax = fmaf(p0, h0.x, ax); ay = fmaf(p0, h0.y, ay);
    }
    const float inv = 1.0f / (den + 1e-16f);
    float vx = ax * inv + bias[hl * 2];
    float vy = ay * inv + bias[hl * 2 + 1];
    if (mode == 1) {
      vx = fmaxf(vx, 0.f);
      vy = fmaxf(vy, 0.f);
      hout[node * 32 + hl] = __floats2half2_rn(vx, vy);
    } else {
      *(float2*)(fout + node * 64 + hl * 2) = make_float2(vx, vy);
    }
  }
}

// Fused persistent kernel: gemm1 -> agg1 -> gemm2 -> agg2 with grid barriers.
__global__ __launch_bounds__(256, 2) void fused_gat(
    const float* __restrict__ x, const ushort* __restrict__ wt1,
    const ushort* __restrict__ wt2,
    const int* __restrict__ ccol, const int* __restrict__ start,
    const int* __restrict__ endp,
    const float* __restrict__ b1, const float* __restrict__ b2,
    __half* __restrict__ hbuf, __half* __restrict__ xbuf_h,
    float* __restrict__ as_, float* __restrict__ ad_, float* __restrict__ out,
    int n, int* __restrict__ bar) {
  __shared__ _Float16 hs[64 * 88];
  __shared__ float att[64 * 12];
  const int ntiles = (n + 63) >> 6;
  const int goal = gridDim.x;

  gemm_phase<256, false>(x, wt1, hbuf, as_, ad_, n, ntiles, hs, att);
  gsync(bar, 0, goal);
  agg_phase(ccol, start, endp, as_, ad_, (const __half2*)hbuf, b1,
            nullptr, (__half2*)xbuf_h, n, 1);
  gsync(bar, 1, goal);
  gemm_phase<64, true>(xbuf_h, wt2, hbuf, as_, ad_, n, ntiles, hs, att);
  gsync(bar, 2, goal);
  agg_phase(ccol, start, endp, as_, ad_, (const __half2*)hbuf, b2,
            out, nullptr, n, 0);
}

extern "C" void kernel_launch(void* const* d_in, const int* in_sizes, int n_in,
                              void* d_out, int out_size, void* d_ws, size_t ws_size,
                              hipStream_t stream) {
  const float* x = (const float*)d_in[0];
  const int* ei = (const int*)d_in[1];
  const float* W1 = (const float*)d_in[2];
  const float* att_s1 = (const float*)d_in[3];
  const float* att_d1 = (const float*)d_in[4];
  const float* b1 = (const float*)d_in[5];
  const float* W2 = (const float*)d_in[6];
  const float* att_s2 = (const float*)d_in[7];
  const float* att_d2 = (const float*)d_in[8];
  const float* b2 = (const float*)d_in[9];

  const int n = in_sizes[0] / 256;  // 100000
  const int E = in_sizes[1] / 2;    // 1600000
  const int* esrc = ei;
  const int* edst = ei + E;
  const int nbuck = (n + 255) >> 8;  // 391

  float* wsf = (float*)d_ws;
  __half* hbuf = (__half*)wsf;
  float* xbuf = wsf + (long long)n * 64;
  float* as_ = xbuf + (long long)n * 64;
  float* ad_ = as_ + (long long)n * 4;
  int* bucket_cnt = (int*)(ad_ + (long long)n * 4);
  int* bucket_base = bucket_cnt + MAXB;
  int* bucket_cursor = bucket_base + MAXB + 1;
  int* start = bucket_cursor + MAXB;
  int* endp = start + n;
  unsigned int* pairs = (unsigned int*)(endp + n);
  int* ccol = (int*)(pairs + E);
  ushort* wt1 = (ushort*)(((uintptr_t)(ccol + E + n) + 15) & ~(uintptr_t)15);
  ushort* wt2 = wt1 + 80 * 256;
  int* bar = (int*)(wt2 + 80 * 64);
  float* out = (float*)d_out;

  const int ebk = (E + CH - 1) / CH;

  // ---- prep ----
  wprep2_kernel<<<(80 * 256 + 255) / 256, 256, 0, stream>>>(W1, att_s1, att_d1, wt1, 256);
  wprep2_kernel<<<(80 * 64 + 255) / 256, 256, 0, stream>>>(W2, att_s2, att_d2, wt2, 64);
  ifill_kernel<<<1, 256, 0, stream>>>(bar, 0, 4);  // barrier counters (per call)

  // ---- CSR bucket build ----
  ifill_kernel<<<(MAXB + 255) / 256, 256, 0, stream>>>(bucket_cnt, 0, MAXB);
  bucket_hist<<<ebk, 256, 0, stream>>>(edst, E, nbuck, bucket_cnt);
  bucket_scan<<<1, 512, 0, stream>>>(bucket_cnt, bucket_base, bucket_cursor, nbuck);
  place_kernel<<<ebk, 256, 0, stream>>>(esrc, edst, E, nbuck, bucket_cursor, pairs);
  bucket_build<<<nbuck, 256, 0, stream>>>(pairs, bucket_base, ccol, start, endp, n);

  // ---- fused persistent 4-phase kernel ----
  fused_gat<<<GRID_FUSED, 256, 0, stream>>>(
      x, wt1, wt2, ccol, start, endp, b1, b2,
      hbuf, (__half*)xbuf, as_, ad_, out, n, bar);
}

// Round 20
// 284.598 us; speedup vs baseline: 2.4930x; 2.4930x over previous
//
#include <hip/hip_runtime.h>
#include <hip/hip_fp16.h>
#include <cstdint>

// 2-layer GAT, PyG GATConv semantics (concat heads, self-loops, segment softmax).
// R20: gemm2 fused INTO agg1 (valid form). R18/R19 post-mortem: bit-identical
// absmax 0.30 across two different implementations proved the W2-aggregation
// commute algebra was wrong (aggregation weight alpha is PER-HEAD; a single
// aggregated y mixes heads). The valid fusion: agg1 computes x2 (f32), stages
// 8 nodes' rows in LDS, applies W2 by VALU matvec (W2 f32, L1-resident),
// stores h2 fp16 + as2/ad2 (per-head 8-lane shfl reduce). agg2 gathers h2
// per head — the R8-R16-proven correct formulation. gemm2 dispatch deleted.
// gemm1 = R14 structure (fused att-dot columns, LDS-bounced stores).
// fp16 gather tables (R8), channel-paired gathers (R9), CSR bucket build (R7).
// Softmax max-subtraction omitted: shift-invariant, |e| <= ~10 so exp() safe in f32.

#define CH 4096
#define MAXB 512
#define SCAP 6144

using f16x8 = __attribute__((ext_vector_type(8))) _Float16;
using f32x4 = __attribute__((ext_vector_type(4))) float;

__device__ __forceinline__ float lrelu(float v) { return fmaxf(v, 0.2f * v); }

__global__ void ifill_kernel(int* __restrict__ p, int v, int n) {
  int i = blockIdx.x * blockDim.x + threadIdx.x;
  if (i < n) p[i] = v;
}

// Augmented W1'^T [80][256] fp16: c<64: W1[k][c]; 64..67: W1_h@att_src1_h;
// 68..71: W1_h@att_dst1_h; 72..79: 0.
__global__ void wprep2_kernel(const float* __restrict__ W,
                              const float* __restrict__ as,
                              const float* __restrict__ ad,
                              ushort* __restrict__ WT, int K) {
  int i = blockIdx.x * 256 + threadIdx.x;
  if (i >= 80 * K) return;
  int c = i / K, k = i % K;
  float v = 0.f;
  if (c < 64) {
    v = W[k * 64 + c];
  } else if (c < 68) {
    int hd = c - 64;
    for (int j = 0; j < 16; ++j) v += W[k * 64 + hd * 16 + j] * as[hd * 16 + j];
  } else if (c < 72) {
    int hd = c - 68;
    for (int j = 0; j < 16; ++j) v += W[k * 64 + hd * 16 + j] * ad[hd * 16 + j];
  }
  WT[c * K + k] = __half_as_ushort(__float2half_rn(v));
}

__global__ __launch_bounds__(256) void bucket_hist(const int* __restrict__ edst,
                                                   int E, int nbuck,
                                                   int* __restrict__ bucket_cnt) {
  __shared__ int hist[MAXB];
  const int t = threadIdx.x;
  for (int j = t; j < MAXB; j += 256) hist[j] = 0;
  __syncthreads();
  const int base = blockIdx.x * CH;
#pragma unroll
  for (int k = 0; k < CH / 256; ++k) {
    int e = base + k * 256 + t;
    if (e < E) atomicAdd(&hist[edst[e] >> 8], 1);
  }
  __syncthreads();
  for (int j = t; j < nbuck; j += 256) {
    int c = hist[j];
    if (c) atomicAdd(&bucket_cnt[j], c);
  }
}

__global__ __launch_bounds__(512) void bucket_scan(const int* __restrict__ bucket_cnt,
                                                   int* __restrict__ bucket_base,
                                                   int* __restrict__ bucket_cursor,
                                                   int nbuck) {
  __shared__ int part[512];
  const int t = threadIdx.x;
  int v = (t < nbuck) ? bucket_cnt[t] : 0;
  part[t] = v;
  __syncthreads();
  for (int off = 1; off < 512; off <<= 1) {
    int u = (t >= off) ? part[t - off] : 0;
    __syncthreads();
    part[t] += u;
    __syncthreads();
  }
  int ex = part[t] - v;
  if (t <= nbuck) {
    int w = (t < nbuck) ? ex : part[nbuck - 1];
    bucket_base[t] = w;
    if (t < nbuck) bucket_cursor[t] = w;
  }
}

__global__ __launch_bounds__(256) void place_kernel(const int* __restrict__ esrc,
                                                    const int* __restrict__ edst,
                                                    int E, int nbuck,
                                                    int* __restrict__ bucket_cursor,
                                                    unsigned int* __restrict__ pairs) {
  __shared__ int hist[MAXB];
  __shared__ int gbase[MAXB];
  __shared__ int rcnt[MAXB];
  const int t = threadIdx.x;
  for (int j = t; j < MAXB; j += 256) { hist[j] = 0; rcnt[j] = 0; }
  __syncthreads();
  const int base = blockIdx.x * CH;
  int b_[CH / 256];
  unsigned int p_[CH / 256];
#pragma unroll
  for (int k = 0; k < CH / 256; ++k) {
    int e = base + k * 256 + t;
    if (e < E) {
      int d = edst[e];
      int s = esrc[e];
      b_[k] = d >> 8;
      p_[k] = ((unsigned int)s << 8) | (unsigned int)(d & 255);
      atomicAdd(&hist[b_[k]], 1);
    } else {
      b_[k] = -1;
    }
  }
  __syncthreads();
  for (int j = t; j < nbuck; j += 256) {
    int c = hist[j];
    gbase[j] = c ? atomicAdd(&bucket_cursor[j], c) : 0;
  }
  __syncthreads();
#pragma unroll
  for (int k = 0; k < CH / 256; ++k) {
    if (b_[k] >= 0) {
      int r = atomicAdd(&rcnt[b_[k]], 1);
      pairs[gbase[b_[k]] + r] = p_[k];
    }
  }
}

__global__ __launch_bounds__(256) void bucket_build(
    const unsigned int* __restrict__ pairs, const int* __restrict__ bucket_base,
    int* __restrict__ ccol, int* __restrict__ start, int* __restrict__ endp,
    int n) {
  __shared__ int cnt[256];
  __shared__ int ls[256];
  __shared__ int csave[256];
  __shared__ int part[256];
  __shared__ int sorted[SCAP];
  const int t = threadIdx.x;
  const int b = blockIdx.x;
  const int d0 = b << 8;
  const int DR = min(256, n - d0);
  const int in_base = bucket_base[b];
  const int nloc = bucket_base[b + 1] - in_base;
  const int out_base = in_base + d0;

  cnt[t] = (t < DR) ? 1 : 0;
  __syncthreads();
  for (int i = t; i < nloc; i += 256)
    atomicAdd(&cnt[pairs[in_base + i] & 255u], 1);
  __syncthreads();
  int c = cnt[t];
  csave[t] = c;
  part[t] = c;
  __syncthreads();
#pragma unroll
  for (int off = 1; off < 256; off <<= 1) {
    int u = (t >= off) ? part[t - off] : 0;
    __syncthreads();
    part[t] += u;
    __syncthreads();
  }
  ls[t] = part[t] - c;
  __syncthreads();
  if (t < DR) {
    int s = out_base + ls[t];
    start[d0 + t] = s;
    endp[d0 + t] = s + csave[t];
    sorted[ls[t]] = d0 + t;
    cnt[t] = 1;
  }
  __syncthreads();
  for (int i = t; i < nloc; i += 256) {
    unsigned int p = pairs[in_base + i];
    int j = (int)(p & 255u);
    int r = atomicAdd(&cnt[j], 1);
    int pos = ls[j] + r;
    if (pos < SCAP) sorted[pos] = (int)(p >> 8);
  }
  __syncthreads();
  int tot = nloc + DR;
  if (tot > SCAP) tot = SCAP;
  for (int i = t; i < tot; i += 256) ccol[out_base + i] = sorted[i];
}

// Layer-1 MFMA GEMM (R14, proven): h1[n][64] fp16 + as1/ad1 via fused att cols.
__global__ __launch_bounds__(256) void gemm1_mfma(
    const float* __restrict__ x, const ushort* __restrict__ wt,
    __half* __restrict__ h, float* __restrict__ as_, float* __restrict__ ad_,
    int n) {
  constexpr int K = 256, NS = K / 32;
  __shared__ _Float16 hs[64 * 88];
  __shared__ float att[64 * 12];
  const int tid = threadIdx.x;
  const int w = tid >> 6;
  const int lane = tid & 63;
  const int lr = lane & 15;
  const int kg = lane >> 4;
  const int row0 = blockIdx.x * 64;

  int rr = row0 + w * 16 + lr;
  if (rr > n - 1) rr = n - 1;

  const ushort* wbase = wt + lr * K + kg * 8;

  f16x8 af[NS];
  {
    float4 av[NS][2];
    const float* xp = x + (long long)rr * K + kg * 8;
#pragma unroll
    for (int s = 0; s < NS; ++s) {
      av[s][0] = *(const float4*)(xp + s * 32);
      av[s][1] = *(const float4*)(xp + s * 32 + 4);
    }
#pragma unroll
    for (int s = 0; s < NS; ++s) {
      af[s][0] = (_Float16)av[s][0].x; af[s][1] = (_Float16)av[s][0].y;
      af[s][2] = (_Float16)av[s][0].z; af[s][3] = (_Float16)av[s][0].w;
      af[s][4] = (_Float16)av[s][1].x; af[s][5] = (_Float16)av[s][1].y;
      af[s][6] = (_Float16)av[s][1].z; af[s][7] = (_Float16)av[s][1].w;
    }
  }

  f32x4 acc[5] = {};
#pragma unroll
  for (int s = 0; s < NS; ++s)
#pragma unroll
    for (int ct = 0; ct < 5; ++ct) {
      f16x8 b = *(const f16x8*)(wbase + ct * 16 * K + s * 32);
      acc[ct] = __builtin_amdgcn_mfma_f32_16x16x32_f16(af[s], b, acc[ct], 0, 0, 0);
    }

  const int orow = w * 16 + kg * 4;
#pragma unroll
  for (int ct = 0; ct < 4; ++ct)
#pragma unroll
    for (int r = 0; r < 4; ++r)
      hs[(orow + r) * 88 + ct * 16 + lr] = (_Float16)acc[ct][r];
  if (lr < 8) {
#pragma unroll
    for (int r = 0; r < 4; ++r)
      att[(orow + r) * 12 + lr] = acc[4][r];
  }
  __syncthreads();
#pragma unroll
  for (int j = 0; j < 2; ++j) {
    int s = tid + j * 256;
    int row = s >> 3, seg = s & 7;
    if (row0 + row < n)
      *(uint4*)(h + (long long)(row0 + row) * 64 + seg * 8) =
          *(const uint4*)&hs[row * 88 + seg * 8];
  }
  if (tid < 64) {
    if (row0 + tid < n)
      *(float4*)(as_ + (long long)(row0 + tid) * 4) = *(const float4*)&att[tid * 12];
  } else if (tid < 128) {
    int t2 = tid - 64;
    if (row0 + t2 < n)
      *(float4*)(ad_ + (long long)(row0 + t2) * 4) = *(const float4*)&att[t2 * 12 + 4];
  }
}

// agg1 + fused layer-2 linear: half-wave per node, 2 nodes/wave (8 per block).
// Phase 1 (proven R9 body): gather h1 -> x2 = relu(agg + b1) in f32, staged in LDS.
// Phase 2: h2 = x2 @ W2 by VALU matvec (W2 f32, L1-resident); store h2 fp16;
// as2/ad2 = per-head dots of h2 with att2 (8-lane shfl reduce).
__global__ __launch_bounds__(256) void agg1_kernel(
    const int* __restrict__ ccol, const int* __restrict__ start,
    const int* __restrict__ endp,
    const float* __restrict__ as1, const float* __restrict__ ad1,
    const __half2* __restrict__ h2in, const float* __restrict__ bias,
    const float* __restrict__ W2, const float* __restrict__ a2s,
    const float* __restrict__ a2d,
    __half2* __restrict__ h2out, float* __restrict__ as2,
    float* __restrict__ ad2, int n) {
  __shared__ float x2s[8][65];
  const int lw = threadIdx.x >> 5;  // local node 0..7
  const int hl = threadIdx.x & 31;
  const int hh = hl >> 3;
  const int node = blockIdx.x * 8 + lw;
  const bool act = node < n;
  const int nodec = act ? node : 0;

  const float adv = ad1[nodec * 4 + hh];
  const int s0i = start[nodec];
  const int d = act ? (endp[nodec] - s0i) : 0;
  const int* cp = ccol + s0i;
  float ax = 0.f, ay = 0.f, den = 0.f;
  int i = 0;
  for (; i + 4 <= d; i += 4) {
    int s0 = cp[i], s1 = cp[i + 1], s2 = cp[i + 2], s3 = cp[i + 3];
    float p0 = __expf(lrelu(as1[s0 * 4 + hh] + adv));
    float p1 = __expf(lrelu(as1[s1 * 4 + hh] + adv));
    float p2 = __expf(lrelu(as1[s2 * 4 + hh] + adv));
    float p3 = __expf(lrelu(as1[s3 * 4 + hh] + adv));
    float2 h0 = __half22float2(h2in[s0 * 32 + hl]);
    float2 h1 = __half22float2(h2in[s1 * 32 + hl]);
    float2 h2v = __half22float2(h2in[s2 * 32 + hl]);
    float2 h3 = __half22float2(h2in[s3 * 32 + hl]);
    den += (p0 + p1) + (p2 + p3);
    ax = fmaf(p0, h0.x, ax); ay = fmaf(p0, h0.y, ay);
    ax = fmaf(p1, h1.x, ax); ay = fmaf(p1, h1.y, ay);
    ax = fmaf(p2, h2v.x, ax); ay = fmaf(p2, h2v.y, ay);
    ax = fmaf(p3, h3.x, ax); ay = fmaf(p3, h3.y, ay);
  }
  for (; i < d; ++i) {
    int s0 = cp[i];
    float p0 = __expf(lrelu(as1[s0 * 4 + hh] + adv));
    float2 h0 = __half22float2(h2in[s0 * 32 + hl]);
    den += p0;
    ax = fmaf(p0, h0.x, ax); ay = fmaf(p0, h0.y, ay);
  }
  const float inv = 1.0f / (den + 1e-16f);
  float vx = act ? fmaxf(ax * inv + bias[hl * 2], 0.f) : 0.f;
  float vy = act ? fmaxf(ay * inv + bias[hl * 2 + 1], 0.f) : 0.f;
  x2s[lw][hl * 2] = vx;
  x2s[lw][hl * 2 + 1] = vy;
  __syncthreads();

  // h2[node][c] = sum_k x2[node][k] * W2[k][c], c = 2hl, 2hl+1.
  float a0 = 0.f, a1 = 0.f;
#pragma unroll 8
  for (int k = 0; k < 64; ++k) {
    float xk = x2s[lw][k];  // LDS broadcast (all 32 lanes same addr)
    float2 wv = *(const float2*)(W2 + k * 64 + hl * 2);  // L1-resident
    a0 = fmaf(xk, wv.x, a0);
    a1 = fmaf(xk, wv.y, a1);
  }
  if (act) h2out[node * 32 + hl] = __floats2half2_rn(a0, a1);

  // as2[node][hh] = sum_{c in head hh} h2[c]*att_src2; 8 lanes cover 16 ch.
  const int j0 = (hl * 2) & 15;
  float ps = a0 * a2s[hh * 16 + j0] + a1 * a2s[hh * 16 + j0 + 1];
  float pd = a0 * a2d[hh * 16 + j0] + a1 * a2d[hh * 16 + j0 + 1];
  ps += __shfl_xor(ps, 1); ps += __shfl_xor(ps, 2); ps += __shfl_xor(ps, 4);
  pd += __shfl_xor(pd, 1); pd += __shfl_xor(pd, 2); pd += __shfl_xor(pd, 4);
  if ((hl & 7) == 0 && act) {
    as2[node * 4 + hh] = ps;
    ad2[node * 4 + hh] = pd;
  }
}

// agg2 (R8-R16 proven form): gather h2 per head, normalize, + b2, f32 out.
__global__ __launch_bounds__(256) void agg2_kernel(
    const int* __restrict__ ccol, const int* __restrict__ start,
    const int* __restrict__ endp,
    const float* __restrict__ as2, const float* __restrict__ ad2,
    const __half2* __restrict__ h2, const float* __restrict__ bias,
    float* __restrict__ out, int n) {
  const int node = blockIdx.x * 8 + (threadIdx.x >> 5);
  if (node >= n) return;
  const int hl = threadIdx.x & 31;
  const int hh = hl >> 3;
  const float adv = ad2[node * 4 + hh];
  const int s0i = start[node];
  const int d = endp[node] - s0i;
  const int* cp = ccol + s0i;
  float ax = 0.f, ay = 0.f, den = 0.f;
  int i = 0;
  for (; i + 4 <= d; i += 4) {
    int s0 = cp[i], s1 = cp[i + 1], s2 = cp[i + 2], s3 = cp[i + 3];
    float p0 = __expf(lrelu(as2[s0 * 4 + hh] + adv));
    float p1 = __expf(lrelu(as2[s1 * 4 + hh] + adv));
    float p2 = __expf(lrelu(as2[s2 * 4 + hh] + adv));
    float p3 = __expf(lrelu(as2[s3 * 4 + hh] + adv));
    float2 h0 = __half22float2(h2[s0 * 32 + hl]);
    float2 h1 = __half22float2(h2[s1 * 32 + hl]);
    float2 h2v = __half22float2(h2[s2 * 32 + hl]);
    float2 h3 = __half22float2(h2[s3 * 32 + hl]);
    den += (p0 + p1) + (p2 + p3);
    ax = fmaf(p0, h0.x, ax); ay = fmaf(p0, h0.y, ay);
    ax = fmaf(p1, h1.x, ax); ay = fmaf(p1, h1.y, ay);
    ax = fmaf(p2, h2v.x, ax); ay = fmaf(p2, h2v.y, ay);
    ax = fmaf(p3, h3.x, ax); ay = fmaf(p3, h3.y, ay);
  }
  for (; i < d; ++i) {
    int s0 = cp[i];
    float p0 = __expf(lrelu(as2[s0 * 4 + hh] + adv));
    float2 h0 = __half22float2(h2[s0 * 32 + hl]);
    den += p0;
    ax = fmaf(p0, h0.x, ax); ay = fmaf(p0, h0.y, ay);
  }
  const float inv = 1.0f / (den + 1e-16f);
  float vx = ax * inv + bias[hl * 2];
  float vy = ay * inv + bias[hl * 2 + 1];
  *(float2*)(out + (long long)node * 64 + hl * 2) = make_float2(vx, vy);
}

extern "C" void kernel_launch(void* const* d_in, const int* in_sizes, int n_in,
                              void* d_out, int out_size, void* d_ws, size_t ws_size,
                              hipStream_t stream) {
  const float* x = (const float*)d_in[0];
  const int* ei = (const int*)d_in[1];
  const float* W1 = (const float*)d_in[2];
  const float* att_s1 = (const float*)d_in[3];
  const float* att_d1 = (const float*)d_in[4];
  const float* b1 = (const float*)d_in[5];
  const float* W2 = (const float*)d_in[6];
  const float* att_s2 = (const float*)d_in[7];
  const float* att_d2 = (const float*)d_in[8];
  const float* b2 = (const float*)d_in[9];

  const int n = in_sizes[0] / 256;  // 100000
  const int E = in_sizes[1] / 2;    // 1600000
  const int* esrc = ei;
  const int* edst = ei + E;
  const int nbuck = (n + 255) >> 8;  // 391

  float* wsf = (float*)d_ws;
  __half* hbuf = (__half*)wsf;                         // [n*64] fp16 h1 table
  __half* h2buf = (__half*)(wsf + (long long)n * 32);  // [n*64] fp16 h2 table
  float* as1 = wsf + (long long)n * 64;                // [n*4]
  float* ad1 = as1 + (long long)n * 4;
  float* as2 = ad1 + (long long)n * 4;
  float* ad2 = as2 + (long long)n * 4;
  int* bucket_cnt = (int*)(ad2 + (long long)n * 4);    // [MAXB]
  int* bucket_base = bucket_cnt + MAXB;                // [MAXB+1]
  int* bucket_cursor = bucket_base + MAXB + 1;         // [MAXB]
  int* start = bucket_cursor + MAXB;                   // [n]
  int* endp = start + n;                               // [n]
  unsigned int* pairs = (unsigned int*)(endp + n);     // [E]
  int* ccol = (int*)(pairs + E);                       // [E+n]
  ushort* wt1 = (ushort*)(((uintptr_t)(ccol + E + n) + 15) & ~(uintptr_t)15);  // [80*256]
  float* out = (float*)d_out;

  const int ebk = (E + CH - 1) / CH;
  const int gb = (n + 63) / 64;
  const int nb1 = (n + 7) / 8;

  // ---- prep ----
  wprep2_kernel<<<(80 * 256 + 255) / 256, 256, 0, stream>>>(W1, att_s1, att_d1, wt1, 256);

  // ---- CSR bucket build ----
  ifill_kernel<<<(MAXB + 255) / 256, 256, 0, stream>>>(bucket_cnt, 0, MAXB);
  bucket_hist<<<ebk, 256, 0, stream>>>(edst, E, nbuck, bucket_cnt);
  bucket_scan<<<1, 512, 0, stream>>>(bucket_cnt, bucket_base, bucket_cursor, nbuck);
  place_kernel<<<ebk, 256, 0, stream>>>(esrc, edst, E, nbuck, bucket_cursor, pairs);
  bucket_build<<<nbuck, 256, 0, stream>>>(pairs, bucket_base, ccol, start, endp, n);

  // ---- layer 1 GEMM + fused agg1/linear2 ----
  gemm1_mfma<<<gb, 256, 0, stream>>>(x, wt1, hbuf, as1, ad1, n);
  agg1_kernel<<<nb1, 256, 0, stream>>>(ccol, start, endp, as1, ad1,
                                       (const __half2*)hbuf, b1,
                                       W2, att_s2, att_d2,
                                       (__half2*)h2buf, as2, ad2, n);

  // ---- layer 2 aggregation ----
  agg2_kernel<<<nb1, 256, 0, stream>>>(ccol, start, endp, as2, ad2,
                                       (const __half2*)h2buf, b2, out, n);
}

// Round 21
// 235.991 us; speedup vs baseline: 3.0065x; 1.2060x over previous
//
#include <hip/hip_runtime.h>
#include <hip/hip_fp16.h>
#include <cstdint>

// 2-layer GAT, PyG GATConv semantics (concat heads, self-loops, segment softmax).
// R21: R20 (gemm2 fused into agg1, per-head-correct) with the matvec operand
// path fixed: W2 staged ONCE per block as fp16 in LDS (8KB; 8x less L1
// traffic than R20's per-thread global W2 loads which made agg1 137us), and
// the matvec reads {x2 LDS broadcast + bank-perfect w2s} per k.
// agg2 = proven per-head gather of h2. gemm1 = R14 structure.
// fp16 gather tables (R8), channel-paired gathers (R9), CSR bucket build (R7).
// Softmax max-subtraction omitted: shift-invariant, |e| <= ~10 so exp() safe in f32.

#define CH 4096
#define MAXB 512
#define SCAP 6144

using f16x8 = __attribute__((ext_vector_type(8))) _Float16;
using f32x4 = __attribute__((ext_vector_type(4))) float;

__device__ __forceinline__ float lrelu(float v) { return fmaxf(v, 0.2f * v); }

__global__ void ifill_kernel(int* __restrict__ p, int v, int n) {
  int i = blockIdx.x * blockDim.x + threadIdx.x;
  if (i < n) p[i] = v;
}

// Augmented W1'^T [80][256] fp16: c<64: W1[k][c]; 64..67: W1_h@att_src1_h;
// 68..71: W1_h@att_dst1_h; 72..79: 0.
__global__ void wprep2_kernel(const float* __restrict__ W,
                              const float* __restrict__ as,
                              const float* __restrict__ ad,
                              ushort* __restrict__ WT, int K) {
  int i = blockIdx.x * 256 + threadIdx.x;
  if (i >= 80 * K) return;
  int c = i / K, k = i % K;
  float v = 0.f;
  if (c < 64) {
    v = W[k * 64 + c];
  } else if (c < 68) {
    int hd = c - 64;
    for (int j = 0; j < 16; ++j) v += W[k * 64 + hd * 16 + j] * as[hd * 16 + j];
  } else if (c < 72) {
    int hd = c - 68;
    for (int j = 0; j < 16; ++j) v += W[k * 64 + hd * 16 + j] * ad[hd * 16 + j];
  }
  WT[c * K + k] = __half_as_ushort(__float2half_rn(v));
}

__global__ __launch_bounds__(256) void bucket_hist(const int* __restrict__ edst,
                                                   int E, int nbuck,
                                                   int* __restrict__ bucket_cnt) {
  __shared__ int hist[MAXB];
  const int t = threadIdx.x;
  for (int j = t; j < MAXB; j += 256) hist[j] = 0;
  __syncthreads();
  const int base = blockIdx.x * CH;
#pragma unroll
  for (int k = 0; k < CH / 256; ++k) {
    int e = base + k * 256 + t;
    if (e < E) atomicAdd(&hist[edst[e] >> 8], 1);
  }
  __syncthreads();
  for (int j = t; j < nbuck; j += 256) {
    int c = hist[j];
    if (c) atomicAdd(&bucket_cnt[j], c);
  }
}

__global__ __launch_bounds__(512) void bucket_scan(const int* __restrict__ bucket_cnt,
                                                   int* __restrict__ bucket_base,
                                                   int* __restrict__ bucket_cursor,
                                                   int nbuck) {
  __shared__ int part[512];
  const int t = threadIdx.x;
  int v = (t < nbuck) ? bucket_cnt[t] : 0;
  part[t] = v;
  __syncthreads();
  for (int off = 1; off < 512; off <<= 1) {
    int u = (t >= off) ? part[t - off] : 0;
    __syncthreads();
    part[t] += u;
    __syncthreads();
  }
  int ex = part[t] - v;
  if (t <= nbuck) {
    int w = (t < nbuck) ? ex : part[nbuck - 1];
    bucket_base[t] = w;
    if (t < nbuck) bucket_cursor[t] = w;
  }
}

__global__ __launch_bounds__(256) void place_kernel(const int* __restrict__ esrc,
                                                    const int* __restrict__ edst,
                                                    int E, int nbuck,
                                                    int* __restrict__ bucket_cursor,
                                                    unsigned int* __restrict__ pairs) {
  __shared__ int hist[MAXB];
  __shared__ int gbase[MAXB];
  __shared__ int rcnt[MAXB];
  const int t = threadIdx.x;
  for (int j = t; j < MAXB; j += 256) { hist[j] = 0; rcnt[j] = 0; }
  __syncthreads();
  const int base = blockIdx.x * CH;
  int b_[CH / 256];
  unsigned int p_[CH / 256];
#pragma unroll
  for (int k = 0; k < CH / 256; ++k) {
    int e = base + k * 256 + t;
    if (e < E) {
      int d = edst[e];
      int s = esrc[e];
      b_[k] = d >> 8;
      p_[k] = ((unsigned int)s << 8) | (unsigned int)(d & 255);
      atomicAdd(&hist[b_[k]], 1);
    } else {
      b_[k] = -1;
    }
  }
  __syncthreads();
  for (int j = t; j < nbuck; j += 256) {
    int c = hist[j];
    gbase[j] = c ? atomicAdd(&bucket_cursor[j], c) : 0;
  }
  __syncthreads();
#pragma unroll
  for (int k = 0; k < CH / 256; ++k) {
    if (b_[k] >= 0) {
      int r = atomicAdd(&rcnt[b_[k]], 1);
      pairs[gbase[b_[k]] + r] = p_[k];
    }
  }
}

__global__ __launch_bounds__(256) void bucket_build(
    const unsigned int* __restrict__ pairs, const int* __restrict__ bucket_base,
    int* __restrict__ ccol, int* __restrict__ start, int* __restrict__ endp,
    int n) {
  __shared__ int cnt[256];
  __shared__ int ls[256];
  __shared__ int csave[256];
  __shared__ int part[256];
  __shared__ int sorted[SCAP];
  const int t = threadIdx.x;
  const int b = blockIdx.x;
  const int d0 = b << 8;
  const int DR = min(256, n - d0);
  const int in_base = bucket_base[b];
  const int nloc = bucket_base[b + 1] - in_base;
  const int out_base = in_base + d0;

  cnt[t] = (t < DR) ? 1 : 0;
  __syncthreads();
  for (int i = t; i < nloc; i += 256)
    atomicAdd(&cnt[pairs[in_base + i] & 255u], 1);
  __syncthreads();
  int c = cnt[t];
  csave[t] = c;
  part[t] = c;
  __syncthreads();
#pragma unroll
  for (int off = 1; off < 256; off <<= 1) {
    int u = (t >= off) ? part[t - off] : 0;
    __syncthreads();
    part[t] += u;
    __syncthreads();
  }
  ls[t] = part[t] - c;
  __syncthreads();
  if (t < DR) {
    int s = out_base + ls[t];
    start[d0 + t] = s;
    endp[d0 + t] = s + csave[t];
    sorted[ls[t]] = d0 + t;
    cnt[t] = 1;
  }
  __syncthreads();
  for (int i = t; i < nloc; i += 256) {
    unsigned int p = pairs[in_base + i];
    int j = (int)(p & 255u);
    int r = atomicAdd(&cnt[j], 1);
    int pos = ls[j] + r;
    if (pos < SCAP) sorted[pos] = (int)(p >> 8);
  }
  __syncthreads();
  int tot = nloc + DR;
  if (tot > SCAP) tot = SCAP;
  for (int i = t; i < tot; i += 256) ccol[out_base + i] = sorted[i];
}

// Layer-1 MFMA GEMM (R14, proven): h1[n][64] fp16 + as1/ad1 via fused att cols.
__global__ __launch_bounds__(256) void gemm1_mfma(
    const float* __restrict__ x, const ushort* __restrict__ wt,
    __half* __restrict__ h, float* __restrict__ as_, float* __restrict__ ad_,
    int n) {
  constexpr int K = 256, NS = K / 32;
  __shared__ _Float16 hs[64 * 88];
  __shared__ float att[64 * 12];
  const int tid = threadIdx.x;
  const int w = tid >> 6;
  const int lane = tid & 63;
  const int lr = lane & 15;
  const int kg = lane >> 4;
  const int row0 = blockIdx.x * 64;

  int rr = row0 + w * 16 + lr;
  if (rr > n - 1) rr = n - 1;

  const ushort* wbase = wt + lr * K + kg * 8;

  f16x8 af[NS];
  {
    float4 av[NS][2];
    const float* xp = x + (long long)rr * K + kg * 8;
#pragma unroll
    for (int s = 0; s < NS; ++s) {
      av[s][0] = *(const float4*)(xp + s * 32);
      av[s][1] = *(const float4*)(xp + s * 32 + 4);
    }
#pragma unroll
    for (int s = 0; s < NS; ++s) {
      af[s][0] = (_Float16)av[s][0].x; af[s][1] = (_Float16)av[s][0].y;
      af[s][2] = (_Float16)av[s][0].z; af[s][3] = (_Float16)av[s][0].w;
      af[s][4] = (_Float16)av[s][1].x; af[s][5] = (_Float16)av[s][1].y;
      af[s][6] = (_Float16)av[s][1].z; af[s][7] = (_Float16)av[s][1].w;
    }
  }

  f32x4 acc[5] = {};
#pragma unroll
  for (int s = 0; s < NS; ++s)
#pragma unroll
    for (int ct = 0; ct < 5; ++ct) {
      f16x8 b = *(const f16x8*)(wbase + ct * 16 * K + s * 32);
      acc[ct] = __builtin_amdgcn_mfma_f32_16x16x32_f16(af[s], b, acc[ct], 0, 0, 0);
    }

  const int orow = w * 16 + kg * 4;
#pragma unroll
  for (int ct = 0; ct < 4; ++ct)
#pragma unroll
    for (int r = 0; r < 4; ++r)
      hs[(orow + r) * 88 + ct * 16 + lr] = (_Float16)acc[ct][r];
  if (lr < 8) {
#pragma unroll
    for (int r = 0; r < 4; ++r)
      att[(orow + r) * 12 + lr] = acc[4][r];
  }
  __syncthreads();
#pragma unroll
  for (int j = 0; j < 2; ++j) {
    int s = tid + j * 256;
    int row = s >> 3, seg = s & 7;
    if (row0 + row < n)
      *(uint4*)(h + (long long)(row0 + row) * 64 + seg * 8) =
          *(const uint4*)&hs[row * 88 + seg * 8];
  }
  if (tid < 64) {
    if (row0 + tid < n)
      *(float4*)(as_ + (long long)(row0 + tid) * 4) = *(const float4*)&att[tid * 12];
  } else if (tid < 128) {
    int t2 = tid - 64;
    if (row0 + t2 < n)
      *(float4*)(ad_ + (long long)(row0 + t2) * 4) = *(const float4*)&att[t2 * 12 + 4];
  }
}

// agg1 + fused layer-2 linear. Phase 1 (R9 body): gather h1 -> x2 f32 in LDS.
// Phase 2: h2 = x2 @ W2 via LDS-staged fp16 W2 (8KB; bank-perfect reads);
// store h2 fp16 + as2/ad2 (per-head 8-lane shfl reduce).
__global__ __launch_bounds__(256) void agg1_kernel(
    const int* __restrict__ ccol, const int* __restrict__ start,
    const int* __restrict__ endp,
    const float* __restrict__ as1, const float* __restrict__ ad1,
    const __half2* __restrict__ h2in, const float* __restrict__ bias,
    const float* __restrict__ W2, const float* __restrict__ a2s,
    const float* __restrict__ a2d,
    __half2* __restrict__ h2out, float* __restrict__ as2,
    float* __restrict__ ad2, int n) {
  __shared__ float x2s[8][65];
  __shared__ __half2 w2s[64 * 32];  // [k][c2] fp16 pairs, 8KB
  const int t = threadIdx.x;
  // Stage W2 -> fp16 LDS once per block (16KB f32 read once, coalesced).
  for (int i = t; i < 2048; i += 256) {
    float2 wv = *(const float2*)(W2 + i * 2);
    w2s[i] = __floats2half2_rn(wv.x, wv.y);
  }

  const int lw = t >> 5;  // local node 0..7
  const int hl = t & 31;
  const int hh = hl >> 3;
  const int node = blockIdx.x * 8 + lw;
  const bool act = node < n;
  const int nodec = act ? node : 0;

  const float adv = ad1[nodec * 4 + hh];
  const int s0i = start[nodec];
  const int d = act ? (endp[nodec] - s0i) : 0;
  const int* cp = ccol + s0i;
  float ax = 0.f, ay = 0.f, den = 0.f;
  int i = 0;
  for (; i + 4 <= d; i += 4) {
    int s0 = cp[i], s1 = cp[i + 1], s2 = cp[i + 2], s3 = cp[i + 3];
    float p0 = __expf(lrelu(as1[s0 * 4 + hh] + adv));
    float p1 = __expf(lrelu(as1[s1 * 4 + hh] + adv));
    float p2 = __expf(lrelu(as1[s2 * 4 + hh] + adv));
    float p3 = __expf(lrelu(as1[s3 * 4 + hh] + adv));
    float2 h0 = __half22float2(h2in[s0 * 32 + hl]);
    float2 h1 = __half22float2(h2in[s1 * 32 + hl]);
    float2 h2v = __half22float2(h2in[s2 * 32 + hl]);
    float2 h3 = __half22float2(h2in[s3 * 32 + hl]);
    den += (p0 + p1) + (p2 + p3);
    ax = fmaf(p0, h0.x, ax); ay = fmaf(p0, h0.y, ay);
    ax = fmaf(p1, h1.x, ax); ay = fmaf(p1, h1.y, ay);
    ax = fmaf(p2, h2v.x, ax); ay = fmaf(p2, h2v.y, ay);
    ax = fmaf(p3, h3.x, ax); ay = fmaf(p3, h3.y, ay);
  }
  for (; i < d; ++i) {
    int s0 = cp[i];
    float p0 = __expf(lrelu(as1[s0 * 4 + hh] + adv));
    float2 h0 = __half22float2(h2in[s0 * 32 + hl]);
    den += p0;
    ax = fmaf(p0, h0.x, ax); ay = fmaf(p0, h0.y, ay);
  }
  const float inv = 1.0f / (den + 1e-16f);
  float vx = act ? fmaxf(ax * inv + bias[hl * 2], 0.f) : 0.f;
  float vy = act ? fmaxf(ay * inv + bias[hl * 2 + 1], 0.f) : 0.f;
  x2s[lw][hl * 2] = vx;
  x2s[lw][hl * 2 + 1] = vy;
  __syncthreads();  // covers both w2s staging and x2s writes

  // h2[node][c] = sum_k x2[node][k] * W2[k][c], c = 2hl, 2hl+1.
  // x2s[lw][k]: LDS broadcast (2 addrs/wave). w2s[k*32+hl]: bank hl — perfect.
  float a0 = 0.f, a1 = 0.f;
#pragma unroll 8
  for (int k = 0; k < 64; ++k) {
    float xk = x2s[lw][k];
    float2 wv = __half22float2(w2s[k * 32 + hl]);
    a0 = fmaf(xk, wv.x, a0);
    a1 = fmaf(xk, wv.y, a1);
  }
  if (act) h2out[node * 32 + hl] = __floats2half2_rn(a0, a1);

  // as2[node][hh] = sum_{c in head hh} h2[c]*att_src2; 8 lanes cover 16 ch.
  const int j0 = (hl * 2) & 15;
  float ps = a0 * a2s[hh * 16 + j0] + a1 * a2s[hh * 16 + j0 + 1];
  float pd = a0 * a2d[hh * 16 + j0] + a1 * a2d[hh * 16 + j0 + 1];
  ps += __shfl_xor(ps, 1); ps += __shfl_xor(ps, 2); ps += __shfl_xor(ps, 4);
  pd += __shfl_xor(pd, 1); pd += __shfl_xor(pd, 2); pd += __shfl_xor(pd, 4);
  if ((hl & 7) == 0 && act) {
    as2[node * 4 + hh] = ps;
    ad2[node * 4 + hh] = pd;
  }
}

// agg2 (R8-R16 proven form): gather h2 per head, normalize, + b2, f32 out.
__global__ __launch_bounds__(256) void agg2_kernel(
    const int* __restrict__ ccol, const int* __restrict__ start,
    const int* __restrict__ endp,
    const float* __restrict__ as2, const float* __restrict__ ad2,
    const __half2* __restrict__ h2, const float* __restrict__ bias,
    float* __restrict__ out, int n) {
  const int node = blockIdx.x * 8 + (threadIdx.x >> 5);
  if (node >= n) return;
  const int hl = threadIdx.x & 31;
  const int hh = hl >> 3;
  const float adv = ad2[node * 4 + hh];
  const int s0i = start[node];
  const int d = endp[node] - s0i;
  const int* cp = ccol + s0i;
  float ax = 0.f, ay = 0.f, den = 0.f;
  int i = 0;
  for (; i + 4 <= d; i += 4) {
    int s0 = cp[i], s1 = cp[i + 1], s2 = cp[i + 2], s3 = cp[i + 3];
    float p0 = __expf(lrelu(as2[s0 * 4 + hh] + adv));
    float p1 = __expf(lrelu(as2[s1 * 4 + hh] + adv));
    float p2 = __expf(lrelu(as2[s2 * 4 + hh] + adv));
    float p3 = __expf(lrelu(as2[s3 * 4 + hh] + adv));
    float2 h0 = __half22float2(h2[s0 * 32 + hl]);
    float2 h1 = __half22float2(h2[s1 * 32 + hl]);
    float2 h2v = __half22float2(h2[s2 * 32 + hl]);
    float2 h3 = __half22float2(h2[s3 * 32 + hl]);
    den += (p0 + p1) + (p2 + p3);
    ax = fmaf(p0, h0.x, ax); ay = fmaf(p0, h0.y, ay);
    ax = fmaf(p1, h1.x, ax); ay = fmaf(p1, h1.y, ay);
    ax = fmaf(p2, h2v.x, ax); ay = fmaf(p2, h2v.y, ay);
    ax = fmaf(p3, h3.x, ax); ay = fmaf(p3, h3.y, ay);
  }
  for (; i < d; ++i) {
    int s0 = cp[i];
    float p0 = __expf(lrelu(as2[s0 * 4 + hh] + adv));
    float2 h0 = __half22float2(h2[s0 * 32 + hl]);
    den += p0;
    ax = fmaf(p0, h0.x, ax); ay = fmaf(p0, h0.y, ay);
  }
  const float inv = 1.0f / (den + 1e-16f);
  float vx = ax * inv + bias[hl * 2];
  float vy = ay * inv + bias[hl * 2 + 1];
  *(float2*)(out + (long long)node * 64 + hl * 2) = make_float2(vx, vy);
}

extern "C" void kernel_launch(void* const* d_in, const int* in_sizes, int n_in,
                              void* d_out, int out_size, void* d_ws, size_t ws_size,
                              hipStream_t stream) {
  const float* x = (const float*)d_in[0];
  const int* ei = (const int*)d_in[1];
  const float* W1 = (const float*)d_in[2];
  const float* att_s1 = (const float*)d_in[3];
  const float* att_d1 = (const float*)d_in[4];
  const float* b1 = (const float*)d_in[5];
  const float* W2 = (const float*)d_in[6];
  const float* att_s2 = (const float*)d_in[7];
  const float* att_d2 = (const float*)d_in[8];
  const float* b2 = (const float*)d_in[9];

  const int n = in_sizes[0] / 256;  // 100000
  const int E = in_sizes[1] / 2;    // 1600000
  const int* esrc = ei;
  const int* edst = ei + E;
  const int nbuck = (n + 255) >> 8;  // 391

  float* wsf = (float*)d_ws;
  __half* hbuf = (__half*)wsf;                         // [n*64] fp16 h1 table
  __half* h2buf = (__half*)(wsf + (long long)n * 32);  // [n*64] fp16 h2 table
  float* as1 = wsf + (long long)n * 64;                // [n*4]
  float* ad1 = as1 + (long long)n * 4;
  float* as2 = ad1 + (long long)n * 4;
  float* ad2 = as2 + (long long)n * 4;
  int* bucket_cnt = (int*)(ad2 + (long long)n * 4);    // [MAXB]
  int* bucket_base = bucket_cnt + MAXB;                // [MAXB+1]
  int* bucket_cursor = bucket_base + MAXB + 1;         // [MAXB]
  int* start = bucket_cursor + MAXB;                   // [n]
  int* endp = start + n;                               // [n]
  unsigned int* pairs = (unsigned int*)(endp + n);     // [E]
  int* ccol = (int*)(pairs + E);                       // [E+n]
  ushort* wt1 = (ushort*)(((uintptr_t)(ccol + E + n) + 15) & ~(uintptr_t)15);  // [80*256]
  float* out = (float*)d_out;

  const int ebk = (E + CH - 1) / CH;
  const int gb = (n + 63) / 64;
  const int nb1 = (n + 7) / 8;

  // ---- prep ----
  wprep2_kernel<<<(80 * 256 + 255) / 256, 256, 0, stream>>>(W1, att_s1, att_d1, wt1, 256);

  // ---- CSR bucket build ----
  ifill_kernel<<<(MAXB + 255) / 256, 256, 0, stream>>>(bucket_cnt, 0, MAXB);
  bucket_hist<<<ebk, 256, 0, stream>>>(edst, E, nbuck, bucket_cnt);
  bucket_scan<<<1, 512, 0, stream>>>(bucket_cnt, bucket_base, bucket_cursor, nbuck);
  place_kernel<<<ebk, 256, 0, stream>>>(esrc, edst, E, nbuck, bucket_cursor, pairs);
  bucket_build<<<nbuck, 256, 0, stream>>>(pairs, bucket_base, ccol, start, endp, n);

  // ---- layer 1 GEMM + fused agg1/linear2 ----
  gemm1_mfma<<<gb, 256, 0, stream>>>(x, wt1, hbuf, as1, ad1, n);
  agg1_kernel<<<nb1, 256, 0, stream>>>(ccol, start, endp, as1, ad1,
                                       (const __half2*)hbuf, b1,
                                       W2, att_s2, att_d2,
                                       (__half2*)h2buf, as2, ad2, n);

  // ---- layer 2 aggregation ----
  agg2_kernel<<<nb1, 256, 0, stream>>>(ccol, start, endp, as2, ad2,
                                       (const __half2*)h2buf, b2, out, n);
}

// Round 22
// 234.291 us; speedup vs baseline: 3.0283x; 1.0073x over previous
//
#include <hip/hip_runtime.h>
#include <hip/hip_fp16.h>
#include <cstdint>

// 2-layer GAT, PyG GATConv semantics (concat heads, self-loops, segment softmax).
// R22: agg1's fused layer-2 linear moved from VALU matvec (R21: ~45us marginal,
// VALUBusy 70%) to a 5-wave MFMA epilogue: block = 320 threads = 10 nodes;
// x2 staged fp16 in LDS [16][72]; wave w computes 16-col tile w of
// x2 @ W2' (W2' = 80-col augmented: 64 W2 + 4 was2 + 4 wad2, via the proven
// R14 wprep2 with K=64) -> h2 + as2/ad2 from 2 MFMAs/wave. D bounced via LDS
// to coalesced stores. Per-head algebra (R20 fix) unchanged.
// agg2 = proven per-head gather of h2. gemm1 = R14 structure.
// fp16 gather tables (R8), channel-paired gathers (R9), CSR bucket build (R7).
// Softmax max-subtraction omitted: shift-invariant, |e| <= ~10 so exp() safe in f32.

#define CH 4096
#define MAXB 512
#define SCAP 6144

using f16x8 = __attribute__((ext_vector_type(8))) _Float16;
using f32x4 = __attribute__((ext_vector_type(4))) float;

__device__ __forceinline__ float lrelu(float v) { return fmaxf(v, 0.2f * v); }

__global__ void ifill_kernel(int* __restrict__ p, int v, int n) {
  int i = blockIdx.x * blockDim.x + threadIdx.x;
  if (i < n) p[i] = v;
}

// Augmented W'^T [80][K] fp16: c<64: W[k][c]; 64..67: W_h@att_src_h;
// 68..71: W_h@att_dst_h; 72..79: 0. (Used for W1 with K=256 and W2 with K=64.)
__global__ void wprep2_kernel(const float* __restrict__ W,
                              const float* __restrict__ as,
                              const float* __restrict__ ad,
                              ushort* __restrict__ WT, int K) {
  int i = blockIdx.x * 256 + threadIdx.x;
  if (i >= 80 * K) return;
  int c = i / K, k = i % K;
  float v = 0.f;
  if (c < 64) {
    v = W[k * 64 + c];
  } else if (c < 68) {
    int hd = c - 64;
    for (int j = 0; j < 16; ++j) v += W[k * 64 + hd * 16 + j] * as[hd * 16 + j];
  } else if (c < 72) {
    int hd = c - 68;
    for (int j = 0; j < 16; ++j) v += W[k * 64 + hd * 16 + j] * ad[hd * 16 + j];
  }
  WT[c * K + k] = __half_as_ushort(__float2half_rn(v));
}

__global__ __launch_bounds__(256) void bucket_hist(const int* __restrict__ edst,
                                                   int E, int nbuck,
                                                   int* __restrict__ bucket_cnt) {
  __shared__ int hist[MAXB];
  const int t = threadIdx.x;
  for (int j = t; j < MAXB; j += 256) hist[j] = 0;
  __syncthreads();
  const int base = blockIdx.x * CH;
#pragma unroll
  for (int k = 0; k < CH / 256; ++k) {
    int e = base + k * 256 + t;
    if (e < E) atomicAdd(&hist[edst[e] >> 8], 1);
  }
  __syncthreads();
  for (int j = t; j < nbuck; j += 256) {
    int c = hist[j];
    if (c) atomicAdd(&bucket_cnt[j], c);
  }
}

__global__ __launch_bounds__(512) void bucket_scan(const int* __restrict__ bucket_cnt,
                                                   int* __restrict__ bucket_base,
                                                   int* __restrict__ bucket_cursor,
                                                   int nbuck) {
  __shared__ int part[512];
  const int t = threadIdx.x;
  int v = (t < nbuck) ? bucket_cnt[t] : 0;
  part[t] = v;
  __syncthreads();
  for (int off = 1; off < 512; off <<= 1) {
    int u = (t >= off) ? part[t - off] : 0;
    __syncthreads();
    part[t] += u;
    __syncthreads();
  }
  int ex = part[t] - v;
  if (t <= nbuck) {
    int w = (t < nbuck) ? ex : part[nbuck - 1];
    bucket_base[t] = w;
    if (t < nbuck) bucket_cursor[t] = w;
  }
}

__global__ __launch_bounds__(256) void place_kernel(const int* __restrict__ esrc,
                                                    const int* __restrict__ edst,
                                                    int E, int nbuck,
                                                    int* __restrict__ bucket_cursor,
                                                    unsigned int* __restrict__ pairs) {
  __shared__ int hist[MAXB];
  __shared__ int gbase[MAXB];
  __shared__ int rcnt[MAXB];
  const int t = threadIdx.x;
  for (int j = t; j < MAXB; j += 256) { hist[j] = 0; rcnt[j] = 0; }
  __syncthreads();
  const int base = blockIdx.x * CH;
  int b_[CH / 256];
  unsigned int p_[CH / 256];
#pragma unroll
  for (int k = 0; k < CH / 256; ++k) {
    int e = base + k * 256 + t;
    if (e < E) {
      int d = edst[e];
      int s = esrc[e];
      b_[k] = d >> 8;
      p_[k] = ((unsigned int)s << 8) | (unsigned int)(d & 255);
      atomicAdd(&hist[b_[k]], 1);
    } else {
      b_[k] = -1;
    }
  }
  __syncthreads();
  for (int j = t; j < nbuck; j += 256) {
    int c = hist[j];
    gbase[j] = c ? atomicAdd(&bucket_cursor[j], c) : 0;
  }
  __syncthreads();
#pragma unroll
  for (int k = 0; k < CH / 256; ++k) {
    if (b_[k] >= 0) {
      int r = atomicAdd(&rcnt[b_[k]], 1);
      pairs[gbase[b_[k]] + r] = p_[k];
    }
  }
}

__global__ __launch_bounds__(256) void bucket_build(
    const unsigned int* __restrict__ pairs, const int* __restrict__ bucket_base,
    int* __restrict__ ccol, int* __restrict__ start, int* __restrict__ endp,
    int n) {
  __shared__ int cnt[256];
  __shared__ int ls[256];
  __shared__ int csave[256];
  __shared__ int part[256];
  __shared__ int sorted[SCAP];
  const int t = threadIdx.x;
  const int b = blockIdx.x;
  const int d0 = b << 8;
  const int DR = min(256, n - d0);
  const int in_base = bucket_base[b];
  const int nloc = bucket_base[b + 1] - in_base;
  const int out_base = in_base + d0;

  cnt[t] = (t < DR) ? 1 : 0;
  __syncthreads();
  for (int i = t; i < nloc; i += 256)
    atomicAdd(&cnt[pairs[in_base + i] & 255u], 1);
  __syncthreads();
  int c = cnt[t];
  csave[t] = c;
  part[t] = c;
  __syncthreads();
#pragma unroll
  for (int off = 1; off < 256; off <<= 1) {
    int u = (t >= off) ? part[t - off] : 0;
    __syncthreads();
    part[t] += u;
    __syncthreads();
  }
  ls[t] = part[t] - c;
  __syncthreads();
  if (t < DR) {
    int s = out_base + ls[t];
    start[d0 + t] = s;
    endp[d0 + t] = s + csave[t];
    sorted[ls[t]] = d0 + t;
    cnt[t] = 1;
  }
  __syncthreads();
  for (int i = t; i < nloc; i += 256) {
    unsigned int p = pairs[in_base + i];
    int j = (int)(p & 255u);
    int r = atomicAdd(&cnt[j], 1);
    int pos = ls[j] + r;
    if (pos < SCAP) sorted[pos] = (int)(p >> 8);
  }
  __syncthreads();
  int tot = nloc + DR;
  if (tot > SCAP) tot = SCAP;
  for (int i = t; i < tot; i += 256) ccol[out_base + i] = sorted[i];
}

// Layer-1 MFMA GEMM (R14, proven): h1[n][64] fp16 + as1/ad1 via fused att cols.
__global__ __launch_bounds__(256) void gemm1_mfma(
    const float* __restrict__ x, const ushort* __restrict__ wt,
    __half* __restrict__ h, float* __restrict__ as_, float* __restrict__ ad_,
    int n) {
  constexpr int K = 256, NS = K / 32;
  __shared__ _Float16 hs[64 * 88];
  __shared__ float att[64 * 12];
  const int tid = threadIdx.x;
  const int w = tid >> 6;
  const int lane = tid & 63;
  const int lr = lane & 15;
  const int kg = lane >> 4;
  const int row0 = blockIdx.x * 64;

  int rr = row0 + w * 16 + lr;
  if (rr > n - 1) rr = n - 1;

  const ushort* wbase = wt + lr * K + kg * 8;

  f16x8 af[NS];
  {
    float4 av[NS][2];
    const float* xp = x + (long long)rr * K + kg * 8;
#pragma unroll
    for (int s = 0; s < NS; ++s) {
      av[s][0] = *(const float4*)(xp + s * 32);
      av[s][1] = *(const float4*)(xp + s * 32 + 4);
    }
#pragma unroll
    for (int s = 0; s < NS; ++s) {
      af[s][0] = (_Float16)av[s][0].x; af[s][1] = (_Float16)av[s][0].y;
      af[s][2] = (_Float16)av[s][0].z; af[s][3] = (_Float16)av[s][0].w;
      af[s][4] = (_Float16)av[s][1].x; af[s][5] = (_Float16)av[s][1].y;
      af[s][6] = (_Float16)av[s][1].z; af[s][7] = (_Float16)av[s][1].w;
    }
  }

  f32x4 acc[5] = {};
#pragma unroll
  for (int s = 0; s < NS; ++s)
#pragma unroll
    for (int ct = 0; ct < 5; ++ct) {
      f16x8 b = *(const f16x8*)(wbase + ct * 16 * K + s * 32);
      acc[ct] = __builtin_amdgcn_mfma_f32_16x16x32_f16(af[s], b, acc[ct], 0, 0, 0);
    }

  const int orow = w * 16 + kg * 4;
#pragma unroll
  for (int ct = 0; ct < 4; ++ct)
#pragma unroll
    for (int r = 0; r < 4; ++r)
      hs[(orow + r) * 88 + ct * 16 + lr] = (_Float16)acc[ct][r];
  if (lr < 8) {
#pragma unroll
    for (int r = 0; r < 4; ++r)
      att[(orow + r) * 12 + lr] = acc[4][r];
  }
  __syncthreads();
#pragma unroll
  for (int j = 0; j < 2; ++j) {
    int s = tid + j * 256;
    int row = s >> 3, seg = s & 7;
    if (row0 + row < n)
      *(uint4*)(h + (long long)(row0 + row) * 64 + seg * 8) =
          *(const uint4*)&hs[row * 88 + seg * 8];
  }
  if (tid < 64) {
    if (row0 + tid < n)
      *(float4*)(as_ + (long long)(row0 + tid) * 4) = *(const float4*)&att[tid * 12];
  } else if (tid < 128) {
    int t2 = tid - 64;
    if (row0 + t2 < n)
      *(float4*)(ad_ + (long long)(row0 + t2) * 4) = *(const float4*)&att[t2 * 12 + 4];
  }
}

// agg1 + fused layer-2 linear via MFMA. 320 threads = 10 nodes (10 half-wave
// gathers, R9 body) -> x2 fp16 staged in LDS [16][72] -> 5 waves each compute
// one 16-col tile of x2 @ W2' (80-col augmented, 2 MFMAs) -> h2 fp16 +
// as2/ad2 via LDS bounce, coalesced stores.
// Fragments: A row=lane&15, k=(lane>>4)*8+j; B col=lane&15 same k;
// D col=lane&15, row=(lane>>4)*4+reg.
__global__ __launch_bounds__(320) void agg1_kernel(
    const int* __restrict__ ccol, const int* __restrict__ start,
    const int* __restrict__ endp,
    const float* __restrict__ as1, const float* __restrict__ ad1,
    const __half2* __restrict__ h2in, const float* __restrict__ bias,
    const ushort* __restrict__ wt2,
    __half* __restrict__ h2out, float* __restrict__ as2,
    float* __restrict__ ad2, int n) {
  __shared__ _Float16 x2s[16 * 72];  // x2 tile (10 rows used), stride 72
  __shared__ _Float16 hs2[16 * 72];  // h2 staging
  __shared__ float att2[16 * 12];    // as2/ad2 staging
  const int t = threadIdx.x;

  // Zero ONLY the pad region (rows 10-15; cols 64-71 of rows 0-9) —
  // disjoint from gather writes, so one barrier before the MFMA suffices.
  for (int i = t; i < 6 * 72; i += 320) x2s[10 * 72 + i] = (_Float16)0.f;
  if (t < 80) x2s[(t >> 3) * 72 + 64 + (t & 7)] = (_Float16)0.f;

  const int lw = t >> 5;  // local node 0..9
  const int hl = t & 31;
  const int hh = hl >> 3;
  const int node = blockIdx.x * 10 + lw;
  const bool act = node < n;
  const int nodec = act ? node : 0;

  const float adv = ad1[nodec * 4 + hh];
  const int s0i = start[nodec];
  const int d = act ? (endp[nodec] - s0i) : 0;
  const int* cp = ccol + s0i;
  float ax = 0.f, ay = 0.f, den = 0.f;
  int i = 0;
  for (; i + 4 <= d; i += 4) {
    int s0 = cp[i], s1 = cp[i + 1], s2 = cp[i + 2], s3 = cp[i + 3];
    float p0 = __expf(lrelu(as1[s0 * 4 + hh] + adv));
    float p1 = __expf(lrelu(as1[s1 * 4 + hh] + adv));
    float p2 = __expf(lrelu(as1[s2 * 4 + hh] + adv));
    float p3 = __expf(lrelu(as1[s3 * 4 + hh] + adv));
    float2 h0 = __half22float2(h2in[s0 * 32 + hl]);
    float2 h1 = __half22float2(h2in[s1 * 32 + hl]);
    float2 h2v = __half22float2(h2in[s2 * 32 + hl]);
    float2 h3 = __half22float2(h2in[s3 * 32 + hl]);
    den += (p0 + p1) + (p2 + p3);
    ax = fmaf(p0, h0.x, ax); ay = fmaf(p0, h0.y, ay);
    ax = fmaf(p1, h1.x, ax); ay = fmaf(p1, h1.y, ay);
    ax = fmaf(p2, h2v.x, ax); ay = fmaf(p2, h2v.y, ay);
    ax = fmaf(p3, h3.x, ax); ay = fmaf(p3, h3.y, ay);
  }
  for (; i < d; ++i) {
    int s0 = cp[i];
    float p0 = __expf(lrelu(as1[s0 * 4 + hh] + adv));
    float2 h0 = __half22float2(h2in[s0 * 32 + hl]);
    den += p0;
    ax = fmaf(p0, h0.x, ax); ay = fmaf(p0, h0.y, ay);
  }
  const float inv = 1.0f / (den + 1e-16f);
  float vx = act ? fmaxf(ax * inv + bias[hl * 2], 0.f) : 0.f;
  float vy = act ? fmaxf(ay * inv + bias[hl * 2 + 1], 0.f) : 0.f;
  x2s[lw * 72 + hl * 2] = (_Float16)vx;
  x2s[lw * 72 + hl * 2 + 1] = (_Float16)vy;
  __syncthreads();

  // MFMA: wave w computes D[:, w*16 .. w*16+15] of x2[16][64] @ W2'[64][80].
  {
    const int w = t >> 6;       // 0..4
    const int lane = t & 63;
    const int lr = lane & 15;   // A row / B col within tile
    const int kg = lane >> 4;
    const ushort* wb = wt2 + (w * 16 + lr) * 64 + kg * 8;
    f32x4 acc = {};
#pragma unroll
    for (int s = 0; s < 2; ++s) {
      f16x8 a = *(const f16x8*)&x2s[lr * 72 + s * 32 + kg * 8];
      f16x8 b = *(const f16x8*)(wb + s * 32);
      acc = __builtin_amdgcn_mfma_f32_16x16x32_f16(a, b, acc, 0, 0, 0);
    }
    // D row = kg*4+r (node), col = w*16+lr.
    if (w < 4) {
#pragma unroll
      for (int r = 0; r < 4; ++r)
        hs2[(kg * 4 + r) * 72 + w * 16 + lr] = (_Float16)acc[r];
    } else if (lr < 8) {
#pragma unroll
      for (int r = 0; r < 4; ++r)
        att2[(kg * 4 + r) * 12 + lr] = acc[r];
    }
  }
  __syncthreads();

  // Coalesced stores: h2 (10 rows x 128B as uint4) + as2/ad2 (float4).
  if (t < 80) {
    int row = t >> 3, seg = t & 7;
    int gn = blockIdx.x * 10 + row;
    if (gn < n)
      *(uint4*)(h2out + (long long)gn * 64 + seg * 8) =
          *(const uint4*)&hs2[row * 72 + seg * 8];
  } else if (t < 90) {
    int row = t - 80;
    int gn = blockIdx.x * 10 + row;
    if (gn < n) *(float4*)(as2 + (long long)gn * 4) = *(const float4*)&att2[row * 12];
  } else if (t < 100) {
    int row = t - 90;
    int gn = blockIdx.x * 10 + row;
    if (gn < n) *(float4*)(ad2 + (long long)gn * 4) = *(const float4*)&att2[row * 12 + 4];
  }
}

// agg2 (R8-R16 proven form): gather h2 per head, normalize, + b2, f32 out.
__global__ __launch_bounds__(256) void agg2_kernel(
    const int* __restrict__ ccol, const int* __restrict__ start,
    const int* __restrict__ endp,
    const float* __restrict__ as2, const float* __restrict__ ad2,
    const __half2* __restrict__ h2, const float* __restrict__ bias,
    float* __restrict__ out, int n) {
  const int node = blockIdx.x * 8 + (threadIdx.x >> 5);
  if (node >= n) return;
  const int hl = threadIdx.x & 31;
  const int hh = hl >> 3;
  const float adv = ad2[node * 4 + hh];
  const int s0i = start[node];
  const int d = endp[node] - s0i;
  const int* cp = ccol + s0i;
  float ax = 0.f, ay = 0.f, den = 0.f;
  int i = 0;
  for (; i + 4 <= d; i += 4) {
    int s0 = cp[i], s1 = cp[i + 1], s2 = cp[i + 2], s3 = cp[i + 3];
    float p0 = __expf(lrelu(as2[s0 * 4 + hh] + adv));
    float p1 = __expf(lrelu(as2[s1 * 4 + hh] + adv));
    float p2 = __expf(lrelu(as2[s2 * 4 + hh] + adv));
    float p3 = __expf(lrelu(as2[s3 * 4 + hh] + adv));
    float2 h0 = __half22float2(h2[s0 * 32 + hl]);
    float2 h1 = __half22float2(h2[s1 * 32 + hl]);
    float2 h2v = __half22float2(h2[s2 * 32 + hl]);
    float2 h3 = __half22float2(h2[s3 * 32 + hl]);
    den += (p0 + p1) + (p2 + p3);
    ax = fmaf(p0, h0.x, ax); ay = fmaf(p0, h0.y, ay);
    ax = fmaf(p1, h1.x, ax); ay = fmaf(p1, h1.y, ay);
    ax = fmaf(p2, h2v.x, ax); ay = fmaf(p2, h2v.y, ay);
    ax = fmaf(p3, h3.x, ax); ay = fmaf(p3, h3.y, ay);
  }
  for (; i < d; ++i) {
    int s0 = cp[i];
    float p0 = __expf(lrelu(as2[s0 * 4 + hh] + adv));
    float2 h0 = __half22float2(h2[s0 * 32 + hl]);
    den += p0;
    ax = fmaf(p0, h0.x, ax); ay = fmaf(p0, h0.y, ay);
  }
  const float inv = 1.0f / (den + 1e-16f);
  float vx = ax * inv + bias[hl * 2];
  float vy = ay * inv + bias[hl * 2 + 1];
  *(float2*)(out + (long long)node * 64 + hl * 2) = make_float2(vx, vy);
}

extern "C" void kernel_launch(void* const* d_in, const int* in_sizes, int n_in,
                              void* d_out, int out_size, void* d_ws, size_t ws_size,
                              hipStream_t stream) {
  const float* x = (const float*)d_in[0];
  const int* ei = (const int*)d_in[1];
  const float* W1 = (const float*)d_in[2];
  const float* att_s1 = (const float*)d_in[3];
  const float* att_d1 = (const float*)d_in[4];
  const float* b1 = (const float*)d_in[5];
  const float* W2 = (const float*)d_in[6];
  const float* att_s2 = (const float*)d_in[7];
  const float* att_d2 = (const float*)d_in[8];
  const float* b2 = (const float*)d_in[9];

  const int n = in_sizes[0] / 256;  // 100000
  const int E = in_sizes[1] / 2;    // 1600000
  const int* esrc = ei;
  const int* edst = ei + E;
  const int nbuck = (n + 255) >> 8;  // 391

  float* wsf = (float*)d_ws;
  __half* hbuf = (__half*)wsf;                         // [n*64] fp16 h1 table
  __half* h2buf = (__half*)(wsf + (long long)n * 32);  // [n*64] fp16 h2 table
  float* as1 = wsf + (long long)n * 64;                // [n*4]
  float* ad1 = as1 + (long long)n * 4;
  float* as2 = ad1 + (long long)n * 4;
  float* ad2 = as2 + (long long)n * 4;
  int* bucket_cnt = (int*)(ad2 + (long long)n * 4);    // [MAXB]
  int* bucket_base = bucket_cnt + MAXB;                // [MAXB+1]
  int* bucket_cursor = bucket_base + MAXB + 1;         // [MAXB]
  int* start = bucket_cursor + MAXB;                   // [n]
  int* endp = start + n;                               // [n]
  unsigned int* pairs = (unsigned int*)(endp + n);     // [E]
  int* ccol = (int*)(pairs + E);                       // [E+n]
  ushort* wt1 = (ushort*)(((uintptr_t)(ccol + E + n) + 15) & ~(uintptr_t)15);  // [80*256]
  ushort* wt2 = wt1 + 80 * 256;                        // [80*64] augmented W2'
  float* out = (float*)d_out;

  const int ebk = (E + CH - 1) / CH;
  const int gb = (n + 63) / 64;
  const int nb1 = (n + 9) / 10;  // agg1: 10 nodes / 320-thread block
  const int nb2 = (n + 7) / 8;   // agg2: 8 nodes / 256-thread block

  // ---- prep: augmented W'^T for both layers ----
  wprep2_kernel<<<(80 * 256 + 255) / 256, 256, 0, stream>>>(W1, att_s1, att_d1, wt1, 256);
  wprep2_kernel<<<(80 * 64 + 255) / 256, 256, 0, stream>>>(W2, att_s2, att_d2, wt2, 64);

  // ---- CSR bucket build ----
  ifill_kernel<<<(MAXB + 255) / 256, 256, 0, stream>>>(bucket_cnt, 0, MAXB);
  bucket_hist<<<ebk, 256, 0, stream>>>(edst, E, nbuck, bucket_cnt);
  bucket_scan<<<1, 512, 0, stream>>>(bucket_cnt, bucket_base, bucket_cursor, nbuck);
  place_kernel<<<ebk, 256, 0, stream>>>(esrc, edst, E, nbuck, bucket_cursor, pairs);
  bucket_build<<<nbuck, 256, 0, stream>>>(pairs, bucket_base, ccol, start, endp, n);

  // ---- layer 1 GEMM + fused agg1/linear2 (MFMA epilogue) ----
  gemm1_mfma<<<gb, 256, 0, stream>>>(x, wt1, hbuf, as1, ad1, n);
  agg1_kernel<<<nb1, 320, 0, stream>>>(ccol, start, endp, as1, ad1,
                                       (const __half2*)hbuf, b1, wt2,
                                       h2buf, as2, ad2, n);

  // ---- layer 2 aggregation ----
  agg2_kernel<<<nb2, 256, 0, stream>>>(ccol, start, endp, as2, ad2,
                                       (const __half2*)h2buf, b2, out, n);
}